// Round 20
// baseline (55.747 us; speedup 1.0000x reference)
//
#include <hip/hip_runtime.h>
#include <stdint.h>

// B=16, S=8192, DIM=128, H=4, KV=2, D=64; tokens = 131072; out [16,16384,128] fp32.
//
// Per token t: Y[896] = W' x_t + bias:
//   ch [0,256):   q, ch = h*64+d
//   ch [256,384): k, ch-256 = kv*64+d
//   ch [384,896): vproj, ch-384 = jg*64 + kp*16 + jm  (kp=kv*2+p)
//        j-remap for float2 stores: j = (jg>>1)*32 + jm*2 + (jg&1)
// coeff[t][ro*4+kp] = 0.125 * sum_d q[2ro+p,d]*k[kv,d]*qmean[d]
// out[row(2t+ro), j] = sum_kp coeff * vproj
//
// R20 = R19 (54.8us) with the block-wide barrier replaced by LDS
// semaphores (per-tile monotone counters, no reuse -> no epoch races).
// qk-waves own all staging (R18 layout) + phase1; v-waves finalize+phase2.
// x buffers 4-deep so qk runs up to 2 tiles ahead; each wave spins only
// on its true dependencies -> lockstep max(role)+skew becomes pipelined.
// Readers of x-tile u = 4 qk (phase1) + 4 v (phase2) -> xdone target 8.
// Fences: lgkmcnt(0) before every signal; volatile spins with "memory"
// clobber. All waves co-resident (1 block/CU) -> spins are deadlock-free.
// Keeps: B-in-regs, NT f32x2 stores, setprio around MFMA clusters.

using short8 = __attribute__((ext_vector_type(8))) short;
using f32x4  = __attribute__((ext_vector_type(4))) float;
using f32x2  = __attribute__((ext_vector_type(2))) float;

constexpr int XSTR = 136;     // bf16 elems per x-row in LDS (128+8)
constexpr int PSTR = 10;      // floats per partial row (8 used)
constexpr int T_TILES = 8;

__device__ __forceinline__ unsigned short f2bf(float f) {
    unsigned int u = __float_as_uint(f);
    u += 0x7FFFu + ((u >> 16) & 1u);          // RNE
    return (unsigned short)(u >> 16);
}

__device__ __forceinline__ void lds_fence() {
    asm volatile("s_waitcnt lgkmcnt(0)" ::: "memory");
}
__device__ __forceinline__ void spin_ge(const volatile int* f, int v) {
    while (*f < v) { }
    asm volatile("" ::: "memory");
}

// ---------------- prep: build W' (bf16 [896][128]) and bias (fp32 [896]) ----------------
__global__ void prep_weights(const float* __restrict__ Wq, const float* __restrict__ bq,
                             const float* __restrict__ Wk, const float* __restrict__ bk,
                             const float* __restrict__ Wv, const float* __restrict__ bv,
                             const float* __restrict__ Wo,
                             unsigned short* __restrict__ Wp, float* __restrict__ bias)
{
    const int ch = blockIdx.x;      // 0..895
    const int c  = threadIdx.x;     // 0..127
    float w, b;
    if (ch < 256) {                 // q
        const int hh = ch & 3, dd = ch >> 2;
        w = Wq[(hh * 64 + dd) * 128 + c];
        b = bq[hh * 64 + dd];
    } else if (ch < 384) {          // k
        const int i = ch - 256;
        const int kvh = i & 1, dd = i >> 1;
        w = Wk[(kvh * 64 + dd) * 128 + c];
        b = bk[kvh * 64 + dd];
    } else {                        // vproj, kp-interleaved, j-remapped for float2 stores
        const int i  = ch - 384;
        const int jg = i >> 6, kp = (i >> 4) & 3, jm = i & 15;
        const int j  = (jg >> 1) * 32 + jm * 2 + (jg & 1);
        const int kv = kp >> 1, p = kp & 1;
        float acc = 0.f, bacc = 0.f;
        #pragma unroll 8
        for (int d = 0; d < 64; ++d) {
            const int idx = kv * 64 + d;
            const int kvh = idx & 1, dd = idx >> 1;
            const float wo = Wo[j * 128 + p * 64 + d];
            acc  += wo * Wv[(kvh * 64 + dd) * 128 + c];
            bacc += wo * bv[kvh * 64 + dd];
        }
        w = acc; b = bacc;
    }
    Wp[ch * 128 + c] = f2bf(w);
    if (c == 0) bias[ch] = b;
}

// ---- x staging helpers: 8 rows per wave call ----
__device__ __forceinline__ void stage8_load(const float* __restrict__ x, int tb, int row0,
                                            int l, float4* xv)
{
    const int row = row0 + (l >> 3);
    const float* src = x + (size_t)(tb + row) * 128 + (l & 7) * 4;
    #pragma unroll
    for (int j = 0; j < 4; ++j) xv[j] = *(const float4*)(src + 32 * j);
}
__device__ __forceinline__ void stage8_write(unsigned short* __restrict__ xb, int row0,
                                             int l, const float4* xv)
{
    const int row = row0 + (l >> 3);
    #pragma unroll
    for (int j = 0; j < 4; ++j) {
        ushort4 s;
        s.x = f2bf(xv[j].x); s.y = f2bf(xv[j].y); s.z = f2bf(xv[j].z); s.w = f2bf(xv[j].w);
        *(ushort4*)&xb[row * XSTR + (l & 7) * 4 + 32 * j] = s;
    }
}

// ---------------- fused main kernel ----------------
__global__ __launch_bounds__(512, 1)
void fused_attn_kernel(const float* __restrict__ x,
                       const unsigned short* __restrict__ Wp,
                       const float* __restrict__ bias,
                       float* __restrict__ out)
{
    __shared__ __align__(16) unsigned short xlds[4][64 * XSTR];       // 69632 B
    __shared__ __align__(16) float partial[2][4][64][PSTR];           // 20480 B
    __shared__ __align__(16) float coeffw[4][64][8];                  //  8192 B
    __shared__ int flg_xready[T_TILES];
    __shared__ int flg_xdone [T_TILES];
    __shared__ int flg_pready[T_TILES];
    __shared__ int flg_pdone [T_TILES];

    const int tid = threadIdx.x;
    const int l   = tid & 63;
    const int wv  = tid >> 6;           // 0..7
    const int lr  = l & 15, lg = l >> 4;
    const int tok0 = blockIdx.x * (T_TILES * 64);

    if (tid < T_TILES) {
        flg_xready[tid] = 0; flg_xdone[tid] = 0;
        flg_pready[tid] = 0; flg_pdone[tid] = 0;
    }
    __syncthreads();

    if (wv < 4) {
        // ===== qk waves: ALL x staging + phase1 producer =====
        const int dc   = wv;
        const int row0 = wv * 16;       // stages rows wv*16 .. wv*16+15
        int chb[6];
        #pragma unroll
        for (int n = 0; n < 4; ++n) chb[n] = n * 64 + dc * 16;
        chb[4] = 256 + dc * 16;
        chb[5] = 320 + dc * 16;

        short8 areg[24];
        #pragma unroll
        for (int n = 0; n < 6; ++n)
            #pragma unroll
            for (int ks = 0; ks < 4; ++ks)
                areg[n * 4 + ks] = *(const short8*)(Wp + (size_t)(chb[n] + lr) * 128 + ks * 32 + lg * 8);
        f32x4 biasv[6];
        #pragma unroll
        for (int n = 0; n < 6; ++n)
            biasv[n] = *(const f32x4*)(bias + chb[n] + lg * 4);

        auto phase1 = [&](const unsigned short* __restrict__ xb, int pb) {
            #pragma unroll
            for (int p = 0; p < 4; ++p) {       // 16-token passes
                f32x4 acc[6];
                #pragma unroll
                for (int n = 0; n < 6; ++n) acc[n] = (f32x4){0.f, 0.f, 0.f, 0.f};
                __builtin_amdgcn_s_setprio(1);
                #pragma unroll
                for (int ks = 0; ks < 4; ++ks) {
                    short8 bfr = *(const short8*)&xb[(p * 16 + lr) * XSTR + ks * 32 + lg * 8];
                    #pragma unroll
                    for (int n = 0; n < 6; ++n)
                        acc[n] = __builtin_amdgcn_mfma_f32_16x16x32_bf16(
                            areg[n * 4 + ks], bfr, acc[n], 0, 0, 0);
                }
                __builtin_amdgcn_s_setprio(0);
                float pa[8];
                #pragma unroll
                for (int c = 0; c < 8; ++c) pa[c] = 0.f;
                #pragma unroll
                for (int r = 0; r < 4; ++r) {
                    const float q0 = acc[0][r] + biasv[0][r];
                    const float q1 = acc[1][r] + biasv[1][r];
                    const float q2 = acc[2][r] + biasv[2][r];
                    const float q3 = acc[3][r] + biasv[3][r];
                    const float k0v = acc[4][r] + biasv[4][r];
                    const float k1v = acc[5][r] + biasv[5][r];
                    const float qm  = 0.25f * (q0 + q1 + q2 + q3);
                    const float kt0 = k0v * qm, kt1 = k1v * qm;
                    pa[0] += q0 * kt0; pa[1] += q1 * kt0;
                    pa[2] += q0 * kt1; pa[3] += q1 * kt1;
                    pa[4] += q2 * kt0; pa[5] += q3 * kt0;
                    pa[6] += q2 * kt1; pa[7] += q3 * kt1;
                }
                #pragma unroll
                for (int c = 0; c < 8; ++c) pa[c] += __shfl_xor(pa[c], 16);
                #pragma unroll
                for (int c = 0; c < 8; ++c) pa[c] += __shfl_xor(pa[c], 32);
                if (lg == 0) {
                    float* dst = &partial[pb][dc][p * 16 + lr][0];
                    *(float2*)(dst)     = make_float2(pa[0], pa[1]);
                    *(float2*)(dst + 2) = make_float2(pa[2], pa[3]);
                    *(float2*)(dst + 4) = make_float2(pa[4], pa[5]);
                    *(float2*)(dst + 6) = make_float2(pa[6], pa[7]);
                }
            }
        };

        // prologue: stage T0, T1 and signal
        {
            float4 xa[4], xb_[4];
            stage8_load(x, tok0, row0,     l, xa);
            stage8_load(x, tok0, row0 + 8, l, xb_);
            stage8_write(xlds[0], row0,     l, xa);
            stage8_write(xlds[0], row0 + 8, l, xb_);
            lds_fence();
            if (l == 0) atomicAdd(&flg_xready[0], 1);
            stage8_load(x, tok0 + 64, row0,     l, xa);
            stage8_load(x, tok0 + 64, row0 + 8, l, xb_);
            stage8_write(xlds[1], row0,     l, xa);
            stage8_write(xlds[1], row0 + 8, l, xb_);
            lds_fence();
            if (l == 0) atomicAdd(&flg_xready[1], 1);
        }

        for (int u = 0; u < T_TILES; ++u) {
            float4 xa[4], xb_[4];
            const bool do_stage = (u + 2 < T_TILES);
            if (do_stage) {
                stage8_load(x, tok0 + (u + 2) * 64, row0,     l, xa);
                stage8_load(x, tok0 + (u + 2) * 64, row0 + 8, l, xb_);
            }
            if (u >= 2) spin_ge(&flg_pdone[u - 2], 4);   // partial[u&1] free
            spin_ge(&flg_xready[u], 4);                  // x tile u staged
            phase1(xlds[u & 3], u & 1);
            lds_fence();
            if (l == 0) {
                atomicAdd(&flg_pready[u], 1);
                atomicAdd(&flg_xdone[u], 1);             // qk done reading x tile u
            }
            if (do_stage) {
                if (u >= 2) spin_ge(&flg_xdone[u - 2], 8);   // buffer (u+2)&3 free
                stage8_write(xlds[(u + 2) & 3], row0,     l, xa);
                stage8_write(xlds[(u + 2) & 3], row0 + 8, l, xb_);
                lds_fence();
                if (l == 0) atomicAdd(&flg_xready[u + 2], 1);
            }
        }
    } else {
        // ===== v waves: finalize + phase2 consumer (no staging) =====
        const int jgp = wv - 4;

        short8 breg[32];                       // [(j2*4+kp)*4 + ks]
        #pragma unroll
        for (int j2 = 0; j2 < 2; ++j2)
            #pragma unroll
            for (int kp = 0; kp < 4; ++kp)
                #pragma unroll
                for (int ks = 0; ks < 4; ++ks)
                    breg[(j2 * 4 + kp) * 4 + ks] = *(const short8*)
                        (Wp + (size_t)(384 + (jgp * 2 + j2) * 64 + kp * 16 + lr) * 128 + ks * 32 + lg * 8);
        float bvv[2][4];
        #pragma unroll
        for (int j2 = 0; j2 < 2; ++j2)
            #pragma unroll
            for (int kp = 0; kp < 4; ++kp)
                bvv[j2][kp] = bias[384 + (jgp * 2 + j2) * 64 + kp * 16 + lr];

        for (int t = 0; t < T_TILES; ++t) {
            spin_ge(&flg_pready[t], 4);
            // finalize coeffs for tile t (wave-private copy)
            {
                const int pb = t & 1;
                float s[8];
                #pragma unroll
                for (int c = 0; c < 8; ++c) s[c] = 0.f;
                #pragma unroll
                for (int dcc = 0; dcc < 4; ++dcc) {
                    const float* pr = &partial[pb][dcc][l][0];
                    #pragma unroll
                    for (int c = 0; c < 4; ++c) {
                        float2 v = *(const float2*)(pr + 2 * c);
                        s[2 * c] += v.x; s[2 * c + 1] += v.y;
                    }
                }
                float* cw = &coeffw[jgp][l][0];
                *(float2*)(cw)     = make_float2(s[0] * 0.125f, s[1] * 0.125f);
                *(float2*)(cw + 2) = make_float2(s[2] * 0.125f, s[3] * 0.125f);
                *(float2*)(cw + 4) = make_float2(s[4] * 0.125f, s[5] * 0.125f);
                *(float2*)(cw + 6) = make_float2(s[6] * 0.125f, s[7] * 0.125f);
            }
            lds_fence();
            if (l == 0) atomicAdd(&flg_pdone[t], 1);

            spin_ge(&flg_xready[t], 4);
            // phase2(t): MFMA + combine + direct NT float2 stores
            {
                const unsigned short* xb = xlds[t & 3];
                const int g0    = tok0 + t * 64;
                const int bb    = g0 >> 13;
                const int srow0 = bb * 16384 + 2 * (g0 & 8191);
                #pragma unroll
                for (int mf = 0; mf < 4; ++mf) {
                    f32x4 a2[2][4];
                    #pragma unroll
                    for (int j2 = 0; j2 < 2; ++j2)
                        #pragma unroll
                        for (int kp = 0; kp < 4; ++kp)
                            a2[j2][kp] = (f32x4){0.f, 0.f, 0.f, 0.f};
                    __builtin_amdgcn_s_setprio(1);
                    #pragma unroll
                    for (int ks = 0; ks < 4; ++ks) {
                        short8 af = *(const short8*)&xb[(mf * 16 + lr) * XSTR + ks * 32 + lg * 8];
                        #pragma unroll
                        for (int j2 = 0; j2 < 2; ++j2)
                            #pragma unroll
                            for (int kp = 0; kp < 4; ++kp)
                                a2[j2][kp] = __builtin_amdgcn_mfma_f32_16x16x32_bf16(
                                    af, breg[(j2 * 4 + kp) * 4 + ks], a2[j2][kp], 0, 0, 0);
                    }
                    __builtin_amdgcn_s_setprio(0);
                    #pragma unroll
                    for (int r = 0; r < 4; ++r) {
                        const int tokL = lg * 4 + r;
                        const int tok  = mf * 16 + tokL;
                        f32x4 cl = *(const f32x4*)&coeffw[jgp][tok][0];
                        f32x4 ch = *(const f32x4*)&coeffw[jgp][tok][4];
                        f32x2 s0, s1;
                        {
                            const float a0 = a2[0][0][r] + bvv[0][0];
                            const float a1 = a2[0][1][r] + bvv[0][1];
                            const float av = a2[0][2][r] + bvv[0][2];
                            const float a3 = a2[0][3][r] + bvv[0][3];
                            s0[0] = cl[0] * a0 + cl[1] * a1 + cl[2] * av + cl[3] * a3;
                            s1[0] = ch[0] * a0 + ch[1] * a1 + ch[2] * av + ch[3] * a3;
                        }
                        {
                            const float a0 = a2[1][0][r] + bvv[1][0];
                            const float a1 = a2[1][1][r] + bvv[1][1];
                            const float av = a2[1][2][r] + bvv[1][2];
                            const float a3 = a2[1][3][r] + bvv[1][3];
                            s0[1] = cl[0] * a0 + cl[1] * a1 + cl[2] * av + cl[3] * a3;
                            s1[1] = ch[0] * a0 + ch[1] * a1 + ch[2] * av + ch[3] * a3;
                        }
                        const int row = srow0 + 32 * mf + 2 * tokL;
                        float* dst = out + (size_t)row * 128 + jgp * 32 + lr * 2;
                        __builtin_nontemporal_store(s0, (f32x2*)(dst));        // ro=0
                        __builtin_nontemporal_store(s1, (f32x2*)(dst + 128));  // ro=1
                    }
                }
            }
            lds_fence();
            if (l == 0) atomicAdd(&flg_xdone[t], 1);
        }
    }
}

extern "C" void kernel_launch(void* const* d_in, const int* in_sizes, int n_in,
                              void* d_out, int out_size, void* d_ws, size_t ws_size,
                              hipStream_t stream)
{
    (void)in_sizes; (void)n_in; (void)out_size; (void)ws_size;
    const float* x  = (const float*)d_in[0];
    const float* Wq = (const float*)d_in[1];
    const float* bq = (const float*)d_in[2];
    const float* Wk = (const float*)d_in[3];
    const float* bk = (const float*)d_in[4];
    const float* Wv = (const float*)d_in[5];
    const float* bv = (const float*)d_in[6];
    const float* Wo = (const float*)d_in[7];

    unsigned short* Wp   = (unsigned short*)d_ws;                    // 896*128 bf16
    float*          bias = (float*)((char*)d_ws + 896 * 128 * 2);    // 896 fp32

    prep_weights<<<896, 128, 0, stream>>>(Wq, bq, Wk, bk, Wv, bv, Wo, Wp, bias);
    fused_attn_kernel<<<256, 512, 0, stream>>>(x, Wp, bias, (float*)d_out);
}

// Round 21
// 54.404 us; speedup vs baseline: 1.0247x; 1.0247x over previous
//
#include <hip/hip_runtime.h>
#include <stdint.h>

// B=16, S=8192, DIM=128, H=4, KV=2, D=64; tokens = 131072; out [16,16384,128] fp32.
//
// FINAL (= R19, session best 54.8us). Per token t: Y[896] = W' x_t + bias:
//   ch [0,256):   q, ch = h*64+d
//   ch [256,384): k, ch-256 = kv*64+d
//   ch [384,896): vproj, ch-384 = jg*64 + kp*16 + jm  (kp=kv*2+p)
//        j-remap for float2 stores: j = (jg>>1)*32 + jm*2 + (jg&1)
// coeff[t][ro*4+kp] = 0.125 * sum_d q[2ro+p,d]*k[kv,d]*qmean[d]
// out[row(2t+ro), j] = sum_kp coeff * vproj
//
// Structure: 256 blocks x 512 thr (8 waves, 1 block/CU). Waves 0-3 qk
// (phase1, W-on-A swapped MFMA, areg-resident 96 VGPR), waves 4-7 vproj
// (breg-resident, direct NT f32x2 stores). 8 tiles of 64 tokens, 3-buffer
// x pipeline, ONE lgkm-only barrier per iteration (global ops stay in
// flight), s_setprio(1) around MFMA clusters. Wins on this path:
// 198 -> 61 (wave-specialize + B-in-regs) -> 56.3 (no-drain barrier)
// -> 55.2 (NT stores) -> 54.8 (setprio). 14 structural variants all
// regressed; practical floor of this structure ~55us (59% of the
// 201MB/6.3TB/s = 32us traffic floor; exposure = memory-latency jitter
// at the 2-waves/SIMD residency the B-in-regs design requires).

using short8 = __attribute__((ext_vector_type(8))) short;
using f32x4  = __attribute__((ext_vector_type(4))) float;
using f32x2  = __attribute__((ext_vector_type(2))) float;

constexpr int XSTR = 136;     // bf16 elems per x-row in LDS (128+8)
constexpr int PSTR = 10;      // floats per partial row (8 used)
constexpr int T_TILES = 8;

__device__ __forceinline__ unsigned short f2bf(float f) {
    unsigned int u = __float_as_uint(f);
    u += 0x7FFFu + ((u >> 16) & 1u);          // RNE
    return (unsigned short)(u >> 16);
}

// Barrier that waits only on LDS traffic; global loads/stores stay in flight.
__device__ __forceinline__ void barrier_nodrain() {
    asm volatile("s_waitcnt lgkmcnt(0)\n\ts_barrier" ::: "memory");
}

// ---------------- prep: build W' (bf16 [896][128]) and bias (fp32 [896]) ----------------
__global__ void prep_weights(const float* __restrict__ Wq, const float* __restrict__ bq,
                             const float* __restrict__ Wk, const float* __restrict__ bk,
                             const float* __restrict__ Wv, const float* __restrict__ bv,
                             const float* __restrict__ Wo,
                             unsigned short* __restrict__ Wp, float* __restrict__ bias)
{
    const int ch = blockIdx.x;      // 0..895
    const int c  = threadIdx.x;     // 0..127
    float w, b;
    if (ch < 256) {                 // q
        const int hh = ch & 3, dd = ch >> 2;
        w = Wq[(hh * 64 + dd) * 128 + c];
        b = bq[hh * 64 + dd];
    } else if (ch < 384) {          // k
        const int i = ch - 256;
        const int kvh = i & 1, dd = i >> 1;
        w = Wk[(kvh * 64 + dd) * 128 + c];
        b = bk[kvh * 64 + dd];
    } else {                        // vproj, kp-interleaved, j-remapped for float2 stores
        const int i  = ch - 384;
        const int jg = i >> 6, kp = (i >> 4) & 3, jm = i & 15;
        const int j  = (jg >> 1) * 32 + jm * 2 + (jg & 1);
        const int kv = kp >> 1, p = kp & 1;
        float acc = 0.f, bacc = 0.f;
        #pragma unroll 8
        for (int d = 0; d < 64; ++d) {
            const int idx = kv * 64 + d;
            const int kvh = idx & 1, dd = idx >> 1;
            const float wo = Wo[j * 128 + p * 64 + d];
            acc  += wo * Wv[(kvh * 64 + dd) * 128 + c];
            bacc += wo * bv[kvh * 64 + dd];
        }
        w = acc; b = bacc;
    }
    Wp[ch * 128 + c] = f2bf(w);
    if (c == 0) bias[ch] = b;
}

// ---- x staging helpers: 8 rows per wave ----
__device__ __forceinline__ void stage8_load(const float* __restrict__ x, int tb, int row0,
                                            int l, float4* xv)
{
    const int row = row0 + (l >> 3);
    const float* src = x + (size_t)(tb + row) * 128 + (l & 7) * 4;
    #pragma unroll
    for (int j = 0; j < 4; ++j) xv[j] = *(const float4*)(src + 32 * j);
}
__device__ __forceinline__ void stage8_write(unsigned short* __restrict__ xb, int row0,
                                             int l, const float4* xv)
{
    const int row = row0 + (l >> 3);
    #pragma unroll
    for (int j = 0; j < 4; ++j) {
        ushort4 s;
        s.x = f2bf(xv[j].x); s.y = f2bf(xv[j].y); s.z = f2bf(xv[j].z); s.w = f2bf(xv[j].w);
        *(ushort4*)&xb[row * XSTR + (l & 7) * 4 + 32 * j] = s;
    }
}

// ---------------- fused main kernel ----------------
__global__ __launch_bounds__(512, 1)
void fused_attn_kernel(const float* __restrict__ x,
                       const unsigned short* __restrict__ Wp,
                       const float* __restrict__ bias,
                       float* __restrict__ out)
{
    __shared__ __align__(16) unsigned short xlds[3][64 * XSTR];       // 52224 B
    __shared__ __align__(16) float partial[2][4][64][PSTR];           // 20480 B
    __shared__ __align__(16) float coeffw[4][64][8];                  //  8192 B

    const int tid = threadIdx.x;
    const int l   = tid & 63;
    const int wv  = tid >> 6;           // 0..7
    const int lr  = l & 15, lg = l >> 4;
    const int tok0 = blockIdx.x * (T_TILES * 64);

    if (wv < 4) {
        // ================= qk waves: phase1 producer =================
        const int dc = wv;
        int chb[6];
        #pragma unroll
        for (int n = 0; n < 4; ++n) chb[n] = n * 64 + dc * 16;
        chb[4] = 256 + dc * 16;
        chb[5] = 320 + dc * 16;

        short8 areg[24];
        #pragma unroll
        for (int n = 0; n < 6; ++n)
            #pragma unroll
            for (int ks = 0; ks < 4; ++ks)
                areg[n * 4 + ks] = *(const short8*)(Wp + (size_t)(chb[n] + lr) * 128 + ks * 32 + lg * 8);
        f32x4 biasv[6];
        #pragma unroll
        for (int n = 0; n < 6; ++n)
            biasv[n] = *(const f32x4*)(bias + chb[n] + lg * 4);

        auto phase1 = [&](const unsigned short* __restrict__ xb, int pb) {
            #pragma unroll
            for (int p = 0; p < 4; ++p) {       // 16-token passes
                f32x4 acc[6];
                #pragma unroll
                for (int n = 0; n < 6; ++n) acc[n] = (f32x4){0.f, 0.f, 0.f, 0.f};
                __builtin_amdgcn_s_setprio(1);
                #pragma unroll
                for (int ks = 0; ks < 4; ++ks) {
                    short8 bfr = *(const short8*)&xb[(p * 16 + lr) * XSTR + ks * 32 + lg * 8];
                    #pragma unroll
                    for (int n = 0; n < 6; ++n)
                        acc[n] = __builtin_amdgcn_mfma_f32_16x16x32_bf16(
                            areg[n * 4 + ks], bfr, acc[n], 0, 0, 0);
                }
                __builtin_amdgcn_s_setprio(0);
                float pa[8];
                #pragma unroll
                for (int c = 0; c < 8; ++c) pa[c] = 0.f;
                #pragma unroll
                for (int r = 0; r < 4; ++r) {
                    const float q0 = acc[0][r] + biasv[0][r];
                    const float q1 = acc[1][r] + biasv[1][r];
                    const float q2 = acc[2][r] + biasv[2][r];
                    const float q3 = acc[3][r] + biasv[3][r];
                    const float k0v = acc[4][r] + biasv[4][r];
                    const float k1v = acc[5][r] + biasv[5][r];
                    const float qm  = 0.25f * (q0 + q1 + q2 + q3);
                    const float kt0 = k0v * qm, kt1 = k1v * qm;
                    pa[0] += q0 * kt0; pa[1] += q1 * kt0;
                    pa[2] += q0 * kt1; pa[3] += q1 * kt1;
                    pa[4] += q2 * kt0; pa[5] += q3 * kt0;
                    pa[6] += q2 * kt1; pa[7] += q3 * kt1;
                }
                #pragma unroll
                for (int c = 0; c < 8; ++c) pa[c] += __shfl_xor(pa[c], 16);
                #pragma unroll
                for (int c = 0; c < 8; ++c) pa[c] += __shfl_xor(pa[c], 32);
                if (lg == 0) {
                    float* dst = &partial[pb][dc][p * 16 + lr][0];
                    *(float2*)(dst)     = make_float2(pa[0], pa[1]);
                    *(float2*)(dst + 2) = make_float2(pa[2], pa[3]);
                    *(float2*)(dst + 4) = make_float2(pa[4], pa[5]);
                    *(float2*)(dst + 6) = make_float2(pa[6], pa[7]);
                }
            }
        };

        // prologue
        {
            float4 xv[4];
            stage8_load(x, tok0, wv * 8, l, xv);
            stage8_write(xlds[0], wv * 8, l, xv);
        }
        barrier_nodrain();                     // B1: x0 ready
        phase1(xlds[0], 0);
        barrier_nodrain();                     // B2: partial[0] + x1 ready

        for (int t = 0; t < T_TILES; ++t) {
            float4 xv[4];
            const bool do_stage = (t < T_TILES - 2);
            if (do_stage) stage8_load(x, tok0 + (t + 2) * 64, wv * 8, l, xv);
            if (t < T_TILES - 1) phase1(xlds[(t + 1) % 3], (t + 1) & 1);
            if (do_stage) stage8_write(xlds[(t + 2) % 3], wv * 8, l, xv);
            barrier_nodrain();
        }
    } else {
        // ================= v waves: phase2 consumer =================
        const int jgp = wv - 4;

        short8 breg[32];                       // [(j2*4+kp)*4 + ks]
        #pragma unroll
        for (int j2 = 0; j2 < 2; ++j2)
            #pragma unroll
            for (int kp = 0; kp < 4; ++kp)
                #pragma unroll
                for (int ks = 0; ks < 4; ++ks)
                    breg[(j2 * 4 + kp) * 4 + ks] = *(const short8*)
                        (Wp + (size_t)(384 + (jgp * 2 + j2) * 64 + kp * 16 + lr) * 128 + ks * 32 + lg * 8);
        float bvv[2][4];
        #pragma unroll
        for (int j2 = 0; j2 < 2; ++j2)
            #pragma unroll
            for (int kp = 0; kp < 4; ++kp)
                bvv[j2][kp] = bias[384 + (jgp * 2 + j2) * 64 + kp * 16 + lr];

        // prologue: stage tile0 (my 8 rows) + tile1 (16 rows)
        {
            float4 xv[4];
            stage8_load(x, tok0, 32 + jgp * 8, l, xv);
            stage8_write(xlds[0], 32 + jgp * 8, l, xv);
        }
        barrier_nodrain();                     // B1: x0 ready
        {
            float4 xv[4];
            stage8_load(x, tok0 + 64, jgp * 16, l, xv);
            stage8_write(xlds[1], jgp * 16, l, xv);
            stage8_load(x, tok0 + 64, jgp * 16 + 8, l, xv);
            stage8_write(xlds[1], jgp * 16 + 8, l, xv);
        }
        barrier_nodrain();                     // B2

        for (int t = 0; t < T_TILES; ++t) {
            float4 xv[4];
            const bool do_stage = (t < T_TILES - 2);
            if (do_stage) stage8_load(x, tok0 + (t + 2) * 64, 32 + jgp * 8, l, xv);

            // finalize coeffs for tile t (wave-private copy)
            {
                const int pb = t & 1;
                float s[8];
                #pragma unroll
                for (int c = 0; c < 8; ++c) s[c] = 0.f;
                #pragma unroll
                for (int dcc = 0; dcc < 4; ++dcc) {
                    const float* pr = &partial[pb][dcc][l][0];
                    #pragma unroll
                    for (int c = 0; c < 4; ++c) {
                        float2 v = *(const float2*)(pr + 2 * c);
                        s[2 * c] += v.x; s[2 * c + 1] += v.y;
                    }
                }
                float* cw = &coeffw[jgp][l][0];
                *(float2*)(cw)     = make_float2(s[0] * 0.125f, s[1] * 0.125f);
                *(float2*)(cw + 2) = make_float2(s[2] * 0.125f, s[3] * 0.125f);
                *(float2*)(cw + 4) = make_float2(s[4] * 0.125f, s[5] * 0.125f);
                *(float2*)(cw + 6) = make_float2(s[6] * 0.125f, s[7] * 0.125f);
            }

            // phase2(t): MFMA + combine + direct NT float2 stores
            {
                const unsigned short* xb = xlds[t % 3];
                const int g0    = tok0 + t * 64;
                const int bb    = g0 >> 13;
                const int srow0 = bb * 16384 + 2 * (g0 & 8191);
                #pragma unroll
                for (int mf = 0; mf < 4; ++mf) {
                    f32x4 a2[2][4];
                    #pragma unroll
                    for (int j2 = 0; j2 < 2; ++j2)
                        #pragma unroll
                        for (int kp = 0; kp < 4; ++kp)
                            a2[j2][kp] = (f32x4){0.f, 0.f, 0.f, 0.f};
                    __builtin_amdgcn_s_setprio(1);
                    #pragma unroll
                    for (int ks = 0; ks < 4; ++ks) {
                        short8 af = *(const short8*)&xb[(mf * 16 + lr) * XSTR + ks * 32 + lg * 8];
                        #pragma unroll
                        for (int j2 = 0; j2 < 2; ++j2)
                            #pragma unroll
                            for (int kp = 0; kp < 4; ++kp)
                                a2[j2][kp] = __builtin_amdgcn_mfma_f32_16x16x32_bf16(
                                    af, breg[(j2 * 4 + kp) * 4 + ks], a2[j2][kp], 0, 0, 0);
                    }
                    __builtin_amdgcn_s_setprio(0);
                    #pragma unroll
                    for (int r = 0; r < 4; ++r) {
                        const int tokL = lg * 4 + r;
                        const int tok  = mf * 16 + tokL;
                        f32x4 cl = *(const f32x4*)&coeffw[jgp][tok][0];
                        f32x4 ch = *(const f32x4*)&coeffw[jgp][tok][4];
                        f32x2 s0, s1;
                        {
                            const float a0 = a2[0][0][r] + bvv[0][0];
                            const float a1 = a2[0][1][r] + bvv[0][1];
                            const float av = a2[0][2][r] + bvv[0][2];
                            const float a3 = a2[0][3][r] + bvv[0][3];
                            s0[0] = cl[0] * a0 + cl[1] * a1 + cl[2] * av + cl[3] * a3;
                            s1[0] = ch[0] * a0 + ch[1] * a1 + ch[2] * av + ch[3] * a3;
                        }
                        {
                            const float a0 = a2[1][0][r] + bvv[1][0];
                            const float a1 = a2[1][1][r] + bvv[1][1];
                            const float av = a2[1][2][r] + bvv[1][2];
                            const float a3 = a2[1][3][r] + bvv[1][3];
                            s0[1] = cl[0] * a0 + cl[1] * a1 + cl[2] * av + cl[3] * a3;
                            s1[1] = ch[0] * a0 + ch[1] * a1 + ch[2] * av + ch[3] * a3;
                        }
                        const int row = srow0 + 32 * mf + 2 * tokL;
                        float* dst = out + (size_t)row * 128 + jgp * 32 + lr * 2;
                        __builtin_nontemporal_store(s0, (f32x2*)(dst));        // ro=0
                        __builtin_nontemporal_store(s1, (f32x2*)(dst + 128));  // ro=1
                    }
                }
            }

            if (do_stage) stage8_write(xlds[(t + 2) % 3], 32 + jgp * 8, l, xv);
            barrier_nodrain();
        }
    }
}

extern "C" void kernel_launch(void* const* d_in, const int* in_sizes, int n_in,
                              void* d_out, int out_size, void* d_ws, size_t ws_size,
                              hipStream_t stream)
{
    (void)in_sizes; (void)n_in; (void)out_size; (void)ws_size;
    const float* x  = (const float*)d_in[0];
    const float* Wq = (const float*)d_in[1];
    const float* bq = (const float*)d_in[2];
    const float* Wk = (const float*)d_in[3];
    const float* bk = (const float*)d_in[4];
    const float* Wv = (const float*)d_in[5];
    const float* bv = (const float*)d_in[6];
    const float* Wo = (const float*)d_in[7];

    unsigned short* Wp   = (unsigned short*)d_ws;                    // 896*128 bf16
    float*          bias = (float*)((char*)d_ws + 896 * 128 * 2);    // 896 fp32

    prep_weights<<<896, 128, 0, stream>>>(Wq, bq, Wk, bk, Wv, bv, Wo, Wp, bias);
    fused_attn_kernel<<<256, 512, 0, stream>>>(x, Wp, bias, (float*)d_out);
}